// Round 1
// baseline (497.616 us; speedup 1.0000x reference)
//
#include <hip/hip_runtime.h>
#include <hip/hip_bf16.h>
#include <stdint.h>

#define N_SRC_C 100000
#define N_DST_C 100000
#define E_C     1600000
#define IN_FC   256
#define HEADS_C 8
#define OUT_FC  32
#define HF_C    256

typedef float f32x4_t __attribute__((ext_vector_type(4)));
typedef short s16x8_t __attribute__((ext_vector_type(8)));

static __device__ __forceinline__ unsigned short f2bf(float f) {
    union { __hip_bfloat16 h; unsigned short u; } cv;
    cv.h = __float2bfloat16(f);
    return cv.u;
}
static __device__ __forceinline__ float bf2f(unsigned short u) {
    return __uint_as_float(((unsigned int)u) << 16);
}

// ---------------- K0a: Wvq = Wv @ Wq  [256,8], bvq = bv@Wq + bq ----------------
__global__ __launch_bounds__(256) void k_make_wvq(
    const float* __restrict__ Wv, const float* __restrict__ bv,
    const float* __restrict__ Wq, const float* __restrict__ bq,
    float* __restrict__ Wvq, float* __restrict__ bvq) {
    __shared__ float Wqs[HF_C * HEADS_C];
    const int tid = threadIdx.x;
    for (int i = tid; i < HF_C * HEADS_C; i += 256) Wqs[i] = Wq[i];
    __syncthreads();
    float acc[HEADS_C];
#pragma unroll
    for (int h = 0; h < HEADS_C; ++h) acc[h] = 0.f;
    for (int t = 0; t < HF_C; ++t) {
        float v = Wv[tid * HF_C + t];
#pragma unroll
        for (int h = 0; h < HEADS_C; ++h) acc[h] += v * Wqs[t * HEADS_C + h];
    }
#pragma unroll
    for (int h = 0; h < HEADS_C; ++h) Wvq[tid * HEADS_C + h] = acc[h];
    if (tid < HEADS_C) {
        float s = bq[tid];
        for (int t = 0; t < HF_C; ++t) s += bv[t] * Wqs[t * HEADS_C + tid];
        bvq[tid] = s;
    }
}

// ---------------- K0b: WT[n][k] = bf16(Wv[k][n]) ----------------
__global__ __launch_bounds__(256) void k_transpose_wv(
    const float* __restrict__ Wv, unsigned short* __restrict__ WT) {
    int i = blockIdx.x * 256 + threadIdx.x;   // grid 256 -> 65536
    int n = i >> 8, kk = i & 255;
    WT[n * IN_FC + kk] = f2bf(Wv[kk * HF_C + n]);
}

// ---------------- K0c: CSR offsets via binary search (dst_idx sorted) ----------------
__global__ __launch_bounds__(256) void k_make_offsets(
    const int* __restrict__ dst_idx, int* __restrict__ off) {
    int n = blockIdx.x * 256 + threadIdx.x;
    if (n > N_DST_C) return;
    if (n == N_DST_C) { off[n] = E_C; return; }
    int lo = 0, hi = E_C;
    while (lo < hi) {
        int mid = (lo + hi) >> 1;
        if (dst_idx[mid] < n) lo = mid + 1; else hi = mid;
    }
    off[n] = lo;
}

// ---------------- K1: h_src = bf16(x_src @ Wv + bv), MFMA 16x16x32 ----------------
#define BM 64
#define BKK 32
#define APITCH 40   // 32 + 8 pad (16B) -> conflict-light ds_read_b128

__global__ __launch_bounds__(256) void k_gemm_h(
    const float* __restrict__ X, const unsigned short* __restrict__ WT,
    const float* __restrict__ bv, unsigned short* __restrict__ H) {
    __shared__ unsigned short As[BM * APITCH];    // 5120 B
    __shared__ unsigned short Bs[HF_C * APITCH];  // 20480 B
    const int tid = threadIdx.x;
    const int lane = tid & 63;
    const int wave = tid >> 6;
    const int row0 = blockIdx.x * BM;

    f32x4_t acc[16];
    const f32x4_t z = {0.f, 0.f, 0.f, 0.f};
#pragma unroll
    for (int i = 0; i < 16; ++i) acc[i] = z;

    for (int k0 = 0; k0 < IN_FC; k0 += BKK) {
        // A tile: 64 rows x 32 f32 -> bf16 (512 float4 chunks, 2 per thread)
#pragma unroll
        for (int i = 0; i < 2; ++i) {
            int c = tid + i * 256;
            int r = c >> 3, cc = c & 7;
            int gr = row0 + r; if (gr >= N_SRC_C) gr = N_SRC_C - 1;
            f32x4_t xv = *(const f32x4_t*)(X + (size_t)gr * IN_FC + k0 + cc * 4);
            unsigned int u0 = (unsigned int)f2bf(xv[0]) | ((unsigned int)f2bf(xv[1]) << 16);
            unsigned int u1 = (unsigned int)f2bf(xv[2]) | ((unsigned int)f2bf(xv[3]) << 16);
            uint2 uu; uu.x = u0; uu.y = u1;
            *(uint2*)(As + r * APITCH + cc * 4) = uu;
        }
        // B tile (transposed Wv): 256 rows x 32 bf16 (1024 x 16B chunks, 4/thread)
#pragma unroll
        for (int i = 0; i < 4; ++i) {
            int c = tid + i * 256;
            int n = c >> 2, ii = c & 3;
            uint4 v = *(const uint4*)(WT + (size_t)n * IN_FC + k0 + ii * 8);
            *(uint4*)(Bs + n * APITCH + ii * 8) = v;
        }
        __syncthreads();
        s16x8_t a = *(const s16x8_t*)(As + (wave * 16 + (lane & 15)) * APITCH + (lane >> 4) * 8);
#pragma unroll
        for (int nt = 0; nt < 16; ++nt) {
            s16x8_t b = *(const s16x8_t*)(Bs + (nt * 16 + (lane & 15)) * APITCH + (lane >> 4) * 8);
            acc[nt] = __builtin_amdgcn_mfma_f32_16x16x32_bf16(a, b, acc[nt], 0, 0, 0);
        }
        __syncthreads();
    }
    // epilogue: + bv, cast bf16, store
    const int rb = row0 + wave * 16 + (lane >> 4) * 4;
    const int col0 = lane & 15;
#pragma unroll
    for (int nt = 0; nt < 16; ++nt) {
        int c = nt * 16 + col0;
        float bb = bv[c];
#pragma unroll
        for (int j = 0; j < 4; ++j) {
            int r = rb + j;
            if (r < N_SRC_C) H[(size_t)r * HF_C + c] = f2bf(acc[nt][j] + bb);
        }
    }
}

// ---------------- K2: q = x_dst @ Wvq + bvq (f32 input, wave per row) ----------------
__global__ __launch_bounds__(256) void k_proj_f32(
    const float* __restrict__ X, const float* __restrict__ W8,
    const float* __restrict__ b8, float* __restrict__ outp, int M) {
    __shared__ float Ws[HEADS_C * HF_C];  // transposed: Ws[h][i]
    const int tid = threadIdx.x;
    for (int i = tid; i < HEADS_C * HF_C; i += 256) {
        int h = i >> 8, idx = i & 255;
        Ws[i] = W8[idx * HEADS_C + h];
    }
    __syncthreads();
    const int lane = tid & 63;
    const int row = blockIdx.x * 4 + (tid >> 6);
    if (row >= M) return;
    float x[4];
#pragma unroll
    for (int t = 0; t < 4; ++t) x[t] = X[(size_t)row * HF_C + lane + 64 * t];
    float p[8];
#pragma unroll
    for (int h = 0; h < 8; ++h) p[h] = 0.f;
#pragma unroll
    for (int t = 0; t < 4; ++t) {
        float xv = x[t];
#pragma unroll
        for (int h = 0; h < 8; ++h) p[h] += xv * Ws[h * 256 + lane + 64 * t];
    }
#pragma unroll
    for (int m = 1; m < 64; m <<= 1) {
#pragma unroll
        for (int h = 0; h < 8; ++h) p[h] += __shfl_xor(p[h], m);
    }
    if (lane < 8) outp[(size_t)row * 8 + lane] = p[lane] + b8[lane];
}

// ---------------- K3: k = h_src(bf16) @ Wk + bk ----------------
__global__ __launch_bounds__(256) void k_proj_bf16(
    const unsigned short* __restrict__ X, const float* __restrict__ W8,
    const float* __restrict__ b8, float* __restrict__ outp, int M) {
    __shared__ float Ws[HEADS_C * HF_C];
    const int tid = threadIdx.x;
    for (int i = tid; i < HEADS_C * HF_C; i += 256) {
        int h = i >> 8, idx = i & 255;
        Ws[i] = W8[idx * HEADS_C + h];
    }
    __syncthreads();
    const int lane = tid & 63;
    const int row = blockIdx.x * 4 + (tid >> 6);
    if (row >= M) return;
    float x[4];
#pragma unroll
    for (int t = 0; t < 4; ++t) x[t] = bf2f(X[(size_t)row * HF_C + lane + 64 * t]);
    float p[8];
#pragma unroll
    for (int h = 0; h < 8; ++h) p[h] = 0.f;
#pragma unroll
    for (int t = 0; t < 4; ++t) {
        float xv = x[t];
#pragma unroll
        for (int h = 0; h < 8; ++h) p[h] += xv * Ws[h * 256 + lane + 64 * t];
    }
#pragma unroll
    for (int m = 1; m < 64; m <<= 1) {
#pragma unroll
        for (int h = 0; h < 8; ++h) p[h] += __shfl_xor(p[h], m);
    }
    if (lane < 8) outp[(size_t)row * 8 + lane] = p[lane] + b8[lane];
}

// ---------------- K4: per-dst-node fused softmax + aggregation (wave per node) ----------------
__global__ __launch_bounds__(256) void k_gat_agg(
    const int* __restrict__ src_idx, const int* __restrict__ off,
    const float* __restrict__ q, const float* __restrict__ kk,
    const unsigned short* __restrict__ H, float* __restrict__ outp) {
    const int wv = (blockIdx.x * 256 + threadIdx.x) >> 6;
    const int lane = threadIdx.x & 63;
    if (wv >= N_DST_C) return;
    const int o0 = off[wv], o1 = off[wv + 1];
    const int hl = lane & 7;
    const float q_l = q[(size_t)wv * 8 + hl];
    float m_l = -1e30f, s_l = 0.f;
    // phase 1: online softmax stats; lane -> (edge o0+8k+(lane>>3), head lane&7)
    for (int base = o0; base < o1; base += 8) {
        int e = base + (lane >> 3);
        bool act = e < o1;
        int s = act ? src_idx[e] : 0;
        float kv = kk[(size_t)s * 8 + hl];
        float ev = q_l + kv;
        ev = (ev >= 0.f) ? ev : 0.2f * ev;
        if (!act) ev = -1e30f;
        float cm = ev;
        cm = fmaxf(cm, __shfl_xor(cm, 8));
        cm = fmaxf(cm, __shfl_xor(cm, 16));
        cm = fmaxf(cm, __shfl_xor(cm, 32));
        float mn = fmaxf(m_l, cm);
        float p = act ? __expf(ev - mn) : 0.f;
        p += __shfl_xor(p, 8);
        p += __shfl_xor(p, 16);
        p += __shfl_xor(p, 32);
        s_l = s_l * __expf(m_l - mn) + p;
        m_l = mn;
    }
    // redistribute: lane -> (head lane>>3, feature-group lane&7)
    const float m_a = __shfl(m_l, lane >> 3);
    const float s_a = __shfl(s_l, lane >> 3);
    const float q_a = __shfl(q_l, lane >> 3);
    const float rs = 1.f / (s_a + 1e-9f);
    const int ha = lane >> 3;
    const unsigned short* Hb = H + (size_t)ha * 32 + (lane & 7) * 4;
    float a0 = 0.f, a1 = 0.f, a2 = 0.f, a3 = 0.f;
    // phase 2: aggregate h_src rows, whole wave per edge
    for (int e = o0; e < o1; ++e) {
        int s = src_idx[e];
        float kv = kk[(size_t)s * 8 + ha];
        float ev = q_a + kv;
        ev = (ev >= 0.f) ? ev : 0.2f * ev;
        float wgt = __expf(ev - m_a) * rs;
        ushort4 xv = *(const ushort4*)(Hb + (size_t)s * 256);
        a0 += wgt * bf2f(xv.x);
        a1 += wgt * bf2f(xv.y);
        a2 += wgt * bf2f(xv.z);
        a3 += wgt * bf2f(xv.w);
    }
    // mean over heads: sum across lanes sharing (lane&7), then /8
    a0 += __shfl_xor(a0, 8); a0 += __shfl_xor(a0, 16); a0 += __shfl_xor(a0, 32);
    a1 += __shfl_xor(a1, 8); a1 += __shfl_xor(a1, 16); a1 += __shfl_xor(a1, 32);
    a2 += __shfl_xor(a2, 8); a2 += __shfl_xor(a2, 16); a2 += __shfl_xor(a2, 32);
    a3 += __shfl_xor(a3, 8); a3 += __shfl_xor(a3, 16); a3 += __shfl_xor(a3, 32);
    if (lane < 8) {
        f32x4_t v = {a0 * 0.125f, a1 * 0.125f, a2 * 0.125f, a3 * 0.125f};
        *(f32x4_t*)(outp + (size_t)wv * 32 + lane * 4) = v;
    }
}

extern "C" void kernel_launch(void* const* d_in, const int* in_sizes, int n_in,
                              void* d_out, int out_size, void* d_ws, size_t ws_size,
                              hipStream_t stream) {
    const float* x_src = (const float*)d_in[0];
    const float* x_dst = (const float*)d_in[1];
    const float* Wv    = (const float*)d_in[2];
    const float* bv    = (const float*)d_in[3];
    const float* Wq    = (const float*)d_in[4];
    const float* bq    = (const float*)d_in[5];
    const float* Wk    = (const float*)d_in[6];
    const float* bk    = (const float*)d_in[7];
    const int* src_idx = (const int*)d_in[8];
    const int* dst_idx = (const int*)d_in[9];
    float* out = (float*)d_out;

    char* w = (char*)d_ws;
    unsigned short* H = (unsigned short*)w; w += (size_t)N_SRC_C * HF_C * 2;   // 51.2 MB
    float* q  = (float*)w; w += (size_t)N_DST_C * HEADS_C * 4;                 // 3.2 MB
    float* kk = (float*)w; w += (size_t)N_SRC_C * HEADS_C * 4;                 // 3.2 MB
    int* off  = (int*)w;   w += 400128;                                        // (N+1)*4 rounded
    unsigned short* WT = (unsigned short*)w; w += (size_t)HF_C * IN_FC * 2;    // 128 KB
    float* Wvq = (float*)w; w += (size_t)IN_FC * HEADS_C * 4;                  // 8 KB
    float* bvq = (float*)w; w += 256;

    k_make_wvq<<<dim3(1), dim3(256), 0, stream>>>(Wv, bv, Wq, bq, Wvq, bvq);
    k_transpose_wv<<<dim3(256), dim3(256), 0, stream>>>(Wv, WT);
    k_make_offsets<<<dim3(391), dim3(256), 0, stream>>>(dst_idx, off);
    k_gemm_h<<<dim3((N_SRC_C + BM - 1) / BM), dim3(256), 0, stream>>>(x_src, WT, bv, H);
    k_proj_f32<<<dim3((N_DST_C + 3) / 4), dim3(256), 0, stream>>>(x_dst, Wvq, bvq, q, N_DST_C);
    k_proj_bf16<<<dim3((N_SRC_C + 3) / 4), dim3(256), 0, stream>>>(H, Wk, bk, kk, N_SRC_C);
    k_gat_agg<<<dim3((N_DST_C + 3) / 4), dim3(256), 0, stream>>>(src_idx, off, q, kk, H, out);
}

// Round 2
// 407.990 us; speedup vs baseline: 1.2197x; 1.2197x over previous
//
#include <hip/hip_runtime.h>
#include <hip/hip_bf16.h>
#include <stdint.h>

#define N_SRC_C 100000
#define N_DST_C 100000
#define E_C     1600000
#define IN_FC   256
#define HEADS_C 8
#define OUT_FC  32
#define HF_C    256

typedef float f32x4_t __attribute__((ext_vector_type(4)));
typedef short s16x8_t __attribute__((ext_vector_type(8)));

static __device__ __forceinline__ unsigned short f2bf(float f) {
    union { __hip_bfloat16 h; unsigned short u; } cv;
    cv.h = __float2bfloat16(f);
    return cv.u;
}
static __device__ __forceinline__ float bf2f(unsigned short u) {
    return __uint_as_float(((unsigned int)u) << 16);
}

// ---------------- K0: fused prep ----------------
// blocks 0..255   : Wvq row i = Wv[i,:] @ Wq  (+ transpose WT[i][k]=bf16(Wv[k][i]))
// block  256      : bvq = bv @ Wq + bq
// blocks 257..647 : CSR offsets via binary search (dst_idx sorted)
__global__ __launch_bounds__(256) void k_prep(
    const float* __restrict__ Wv, const float* __restrict__ bv,
    const float* __restrict__ Wq, const float* __restrict__ bq,
    const int* __restrict__ dst_idx,
    unsigned short* __restrict__ WT, float* __restrict__ Wvq,
    float* __restrict__ bvq, int* __restrict__ off) {
    const int b = blockIdx.x;
    const int tid = threadIdx.x;
    if (b < 257) {
        __shared__ float sm[4][8];
        const int i = b;
        float vv = (i < 256) ? Wv[i * HF_C + tid] : bv[tid];
        float pv[8];
#pragma unroll
        for (int h = 0; h < 8; ++h) pv[h] = vv * Wq[tid * 8 + h];
#pragma unroll
        for (int m = 1; m < 64; m <<= 1) {
#pragma unroll
            for (int h = 0; h < 8; ++h) pv[h] += __shfl_xor(pv[h], m);
        }
        const int w = tid >> 6, ln = tid & 63;
#pragma unroll
        for (int h = 0; h < 8; ++h) if (ln == h) sm[w][h] = pv[h];
        __syncthreads();
        if (tid < 8) {
            float s = sm[0][tid] + sm[1][tid] + sm[2][tid] + sm[3][tid];
            if (i < 256) Wvq[i * 8 + tid] = s;
            else bvq[tid] = s + bq[tid];
        }
        if (i < 256) WT[i * IN_FC + tid] = f2bf(Wv[tid * HF_C + i]);
    } else {
        int n = (b - 257) * 256 + tid;
        if (n > N_DST_C) return;
        if (n == N_DST_C) { off[n] = E_C; return; }
        int lo = 0, hi = E_C;
        while (lo < hi) {
            int mid = (lo + hi) >> 1;
            if (dst_idx[mid] < n) lo = mid + 1; else hi = mid;
        }
        off[n] = lo;
    }
}

// ---------------- K1: h_src = bf16(x_src @ Wv + bv), MFMA 16x16x32 ----------------
#define BM 64
#define BKK 32
#define APITCH 40   // 32 + 8 pad (16B) -> conflict-light ds_read_b128

__global__ __launch_bounds__(256) void k_gemm_h(
    const float* __restrict__ X, const unsigned short* __restrict__ WT,
    const float* __restrict__ bv, unsigned short* __restrict__ H) {
    __shared__ unsigned short As[BM * APITCH];    // 5120 B
    __shared__ unsigned short Bs[HF_C * APITCH];  // 20480 B
    const int tid = threadIdx.x;
    const int lane = tid & 63;
    const int wave = tid >> 6;
    const int row0 = blockIdx.x * BM;

    f32x4_t acc[16];
    const f32x4_t z = {0.f, 0.f, 0.f, 0.f};
#pragma unroll
    for (int i = 0; i < 16; ++i) acc[i] = z;

    for (int k0 = 0; k0 < IN_FC; k0 += BKK) {
#pragma unroll
        for (int i = 0; i < 2; ++i) {
            int c = tid + i * 256;
            int r = c >> 3, cc = c & 7;
            int gr = row0 + r; if (gr >= N_SRC_C) gr = N_SRC_C - 1;
            f32x4_t xv = *(const f32x4_t*)(X + (size_t)gr * IN_FC + k0 + cc * 4);
            unsigned int u0 = (unsigned int)f2bf(xv[0]) | ((unsigned int)f2bf(xv[1]) << 16);
            unsigned int u1 = (unsigned int)f2bf(xv[2]) | ((unsigned int)f2bf(xv[3]) << 16);
            uint2 uu; uu.x = u0; uu.y = u1;
            *(uint2*)(As + r * APITCH + cc * 4) = uu;
        }
#pragma unroll
        for (int i = 0; i < 4; ++i) {
            int c = tid + i * 256;
            int n = c >> 2, ii = c & 3;
            uint4 v = *(const uint4*)(WT + (size_t)n * IN_FC + k0 + ii * 8);
            *(uint4*)(Bs + n * APITCH + ii * 8) = v;
        }
        __syncthreads();
        s16x8_t a = *(const s16x8_t*)(As + (wave * 16 + (lane & 15)) * APITCH + (lane >> 4) * 8);
#pragma unroll
        for (int nt = 0; nt < 16; ++nt) {
            s16x8_t bfr = *(const s16x8_t*)(Bs + (nt * 16 + (lane & 15)) * APITCH + (lane >> 4) * 8);
            acc[nt] = __builtin_amdgcn_mfma_f32_16x16x32_bf16(a, bfr, acc[nt], 0, 0, 0);
        }
        __syncthreads();
    }
    const int rb = row0 + wave * 16 + (lane >> 4) * 4;
    const int col0 = lane & 15;
#pragma unroll
    for (int nt = 0; nt < 16; ++nt) {
        int c = nt * 16 + col0;
        float bb = bv[c];
#pragma unroll
        for (int j = 0; j < 4; ++j) {
            int r = rb + j;
            if (r < N_SRC_C) H[(size_t)r * HF_C + c] = f2bf(acc[nt][j] + bb);
        }
    }
}

// ---------------- K2: q = x_dst @ Wvq + bvq (f32 input, wave per row) ----------------
__global__ __launch_bounds__(256) void k_proj_f32(
    const float* __restrict__ X, const float* __restrict__ W8,
    const float* __restrict__ b8, float* __restrict__ outp, int M) {
    __shared__ float Ws[HEADS_C * HF_C];  // transposed: Ws[h][i]
    const int tid = threadIdx.x;
    for (int i = tid; i < HEADS_C * HF_C; i += 256) {
        int h = i >> 8, idx = i & 255;
        Ws[i] = W8[idx * HEADS_C + h];
    }
    __syncthreads();
    const int lane = tid & 63;
    const int row = blockIdx.x * 4 + (tid >> 6);
    if (row >= M) return;
    float x[4];
#pragma unroll
    for (int t = 0; t < 4; ++t) x[t] = X[(size_t)row * HF_C + lane + 64 * t];
    float p[8];
#pragma unroll
    for (int h = 0; h < 8; ++h) p[h] = 0.f;
#pragma unroll
    for (int t = 0; t < 4; ++t) {
        float xv = x[t];
#pragma unroll
        for (int h = 0; h < 8; ++h) p[h] += xv * Ws[h * 256 + lane + 64 * t];
    }
#pragma unroll
    for (int m = 1; m < 64; m <<= 1) {
#pragma unroll
        for (int h = 0; h < 8; ++h) p[h] += __shfl_xor(p[h], m);
    }
    if (lane < 8) outp[(size_t)row * 8 + lane] = p[lane] + b8[lane];
}

// ---------------- K3: k = h_src(bf16) @ Wk + bk ----------------
__global__ __launch_bounds__(256) void k_proj_bf16(
    const unsigned short* __restrict__ X, const float* __restrict__ W8,
    const float* __restrict__ b8, float* __restrict__ outp, int M) {
    __shared__ float Ws[HEADS_C * HF_C];
    const int tid = threadIdx.x;
    for (int i = tid; i < HEADS_C * HF_C; i += 256) {
        int h = i >> 8, idx = i & 255;
        Ws[i] = W8[idx * HEADS_C + h];
    }
    __syncthreads();
    const int lane = tid & 63;
    const int row = blockIdx.x * 4 + (tid >> 6);
    if (row >= M) return;
    float x[4];
#pragma unroll
    for (int t = 0; t < 4; ++t) x[t] = bf2f(X[(size_t)row * HF_C + lane + 64 * t]);
    float p[8];
#pragma unroll
    for (int h = 0; h < 8; ++h) p[h] = 0.f;
#pragma unroll
    for (int t = 0; t < 4; ++t) {
        float xv = x[t];
#pragma unroll
        for (int h = 0; h < 8; ++h) p[h] += xv * Ws[h * 256 + lane + 64 * t];
    }
#pragma unroll
    for (int m = 1; m < 64; m <<= 1) {
#pragma unroll
        for (int h = 0; h < 8; ++h) p[h] += __shfl_xor(p[h], m);
    }
    if (lane < 8) outp[(size_t)row * 8 + lane] = p[lane] + b8[lane];
}

// ---------------- K4: single-pass online-softmax + aggregation (wave per dst) ----------------
// weight layout: lane = 8*e_sub + h_w  (8 edges x 8 heads)
// agg layout:    lane = 8*h_a + fc     (8 heads x 8 feature-chunks of 4)
__global__ __launch_bounds__(256) void k_gat_agg(
    const int* __restrict__ src_idx, const int* __restrict__ off,
    const float* __restrict__ q, const float* __restrict__ kk,
    const unsigned short* __restrict__ H, float* __restrict__ outp) {
    const int wv = (blockIdx.x * 256 + threadIdx.x) >> 6;
    const int lane = threadIdx.x & 63;
    if (wv >= N_DST_C) return;
    const int o0 = off[wv], o1 = off[wv + 1];
    const int e_sub = lane >> 3;
    const int h_w   = lane & 7;
    const int h_a   = lane >> 3;
    const float q_w = q[(size_t)wv * 8 + h_w];

    float m_w = -1e30f;   // running max per head (uniform across e-lanes)
    float den_w = 0.f;    // partial softmax denominator (this lane's e-slice)
    float a0 = 0.f, a1 = 0.f, a2 = 0.f, a3 = 0.f;
    const unsigned short* Hb = H + (size_t)h_a * 32 + (lane & 7) * 4;

    for (int base = o0; base < o1; base += 8) {
        const int rem = o1 - base;            // wave-uniform
        const int e = base + e_sub;
        const bool act = e_sub < rem;
        const int s = act ? src_idx[e] : 0;
        const float kv = kk[(size_t)s * 8 + h_w];
        float ev = q_w + kv;
        ev = (ev >= 0.f) ? ev : 0.2f * ev;
        if (!act) ev = -1e30f;
        // per-head tile max over the 8 edge-sublanes
        float cm = ev;
        cm = fmaxf(cm, __shfl_xor(cm, 8));
        cm = fmaxf(cm, __shfl_xor(cm, 16));
        cm = fmaxf(cm, __shfl_xor(cm, 32));
        if (!__all(cm <= m_w)) {
            float m_new = fmaxf(m_w, cm);
            float sc_w = __expf(m_w - m_new);
            den_w *= sc_w;
            float sc_a = __shfl(sc_w, h_a);   // scale for this lane's agg head
            a0 *= sc_a; a1 *= sc_a; a2 *= sc_a; a3 *= sc_a;
            m_w = m_new;
        }
        const float p = act ? __expf(ev - m_w) : 0.f;
        den_w += p;
        const int ubase = __builtin_amdgcn_readfirstlane(base);
        if (rem >= 8) {
#pragma unroll
            for (int e2 = 0; e2 < 8; ++e2) {
                float wgt = __shfl(p, e2 * 8 + h_a);
                int se = src_idx[ubase + e2];              // scalar load
                ushort4 xv = *(const ushort4*)(Hb + (size_t)se * 256);
                a0 += wgt * bf2f(xv.x); a1 += wgt * bf2f(xv.y);
                a2 += wgt * bf2f(xv.z); a3 += wgt * bf2f(xv.w);
            }
        } else {
            for (int e2 = 0; e2 < rem; ++e2) {
                float wgt = __shfl(p, e2 * 8 + h_a);
                int se = src_idx[ubase + e2];
                ushort4 xv = *(const ushort4*)(Hb + (size_t)se * 256);
                a0 += wgt * bf2f(xv.x); a1 += wgt * bf2f(xv.y);
                a2 += wgt * bf2f(xv.z); a3 += wgt * bf2f(xv.w);
            }
        }
    }
    // softmax denominator: reduce partials over e-slices
    den_w += __shfl_xor(den_w, 8);
    den_w += __shfl_xor(den_w, 16);
    den_w += __shfl_xor(den_w, 32);
    const float rs_w = 1.f / (den_w + 1e-9f);
    const float rs_a = __shfl(rs_w, h_a);
    a0 *= rs_a; a1 *= rs_a; a2 *= rs_a; a3 *= rs_a;
    // mean over heads (reduce across bits 3..5), then /8
    a0 += __shfl_xor(a0, 8); a0 += __shfl_xor(a0, 16); a0 += __shfl_xor(a0, 32);
    a1 += __shfl_xor(a1, 8); a1 += __shfl_xor(a1, 16); a1 += __shfl_xor(a1, 32);
    a2 += __shfl_xor(a2, 8); a2 += __shfl_xor(a2, 16); a2 += __shfl_xor(a2, 32);
    a3 += __shfl_xor(a3, 8); a3 += __shfl_xor(a3, 16); a3 += __shfl_xor(a3, 32);
    if (lane < 8) {
        f32x4_t v = {a0 * 0.125f, a1 * 0.125f, a2 * 0.125f, a3 * 0.125f};
        *(f32x4_t*)(outp + (size_t)wv * 32 + lane * 4) = v;
    }
}

extern "C" void kernel_launch(void* const* d_in, const int* in_sizes, int n_in,
                              void* d_out, int out_size, void* d_ws, size_t ws_size,
                              hipStream_t stream) {
    const float* x_src = (const float*)d_in[0];
    const float* x_dst = (const float*)d_in[1];
    const float* Wv    = (const float*)d_in[2];
    const float* bv    = (const float*)d_in[3];
    const float* Wq    = (const float*)d_in[4];
    const float* bq    = (const float*)d_in[5];
    const float* Wk    = (const float*)d_in[6];
    const float* bk    = (const float*)d_in[7];
    const int* src_idx = (const int*)d_in[8];
    const int* dst_idx = (const int*)d_in[9];
    float* out = (float*)d_out;

    char* w = (char*)d_ws;
    unsigned short* H = (unsigned short*)w; w += (size_t)N_SRC_C * HF_C * 2;   // 51.2 MB
    float* q  = (float*)w; w += (size_t)N_DST_C * HEADS_C * 4;                 // 3.2 MB
    float* kk = (float*)w; w += (size_t)N_SRC_C * HEADS_C * 4;                 // 3.2 MB
    int* off  = (int*)w;   w += 400128;                                        // (N+1)*4 rounded
    unsigned short* WT = (unsigned short*)w; w += (size_t)HF_C * IN_FC * 2;    // 128 KB
    float* Wvq = (float*)w; w += (size_t)IN_FC * HEADS_C * 4;                  // 8 KB
    float* bvq = (float*)w; w += 256;

    k_prep<<<dim3(648), dim3(256), 0, stream>>>(Wv, bv, Wq, bq, dst_idx, WT, Wvq, bvq, off);
    k_gemm_h<<<dim3((N_SRC_C + BM - 1) / BM), dim3(256), 0, stream>>>(x_src, WT, bv, H);
    k_proj_f32<<<dim3((N_DST_C + 3) / 4), dim3(256), 0, stream>>>(x_dst, Wvq, bvq, q, N_DST_C);
    k_proj_bf16<<<dim3((N_SRC_C + 3) / 4), dim3(256), 0, stream>>>(H, Wk, bk, kk, N_SRC_C);
    k_gat_agg<<<dim3((N_DST_C + 3) / 4), dim3(256), 0, stream>>>(src_idx, off, q, kk, H, out);
}

// Round 3
// 343.347 us; speedup vs baseline: 1.4493x; 1.1883x over previous
//
#include <hip/hip_runtime.h>
#include <hip/hip_bf16.h>
#include <stdint.h>

#define N_SRC_C 100000
#define N_DST_C 100000
#define E_C     1600000
#define IN_FC   256
#define HEADS_C 8
#define OUT_FC  32
#define HF_C    256

typedef float f32x4_t __attribute__((ext_vector_type(4)));
typedef short s16x8_t __attribute__((ext_vector_type(8)));

static __device__ __forceinline__ unsigned short f2bf(float f) {
    union { __hip_bfloat16 h; unsigned short u; } cv;
    cv.h = __float2bfloat16(f);
    return cv.u;
}
static __device__ __forceinline__ float bf2f(unsigned short u) {
    return __uint_as_float(((unsigned int)u) << 16);
}

// ---------------- K0: fused prep ----------------
// blocks 0..255 : WT main row i (bf16 Wv^T) + Wvq row i (f32) + Wvk^T row (bf16, rows 256..263)
// block 256     : bvq = bv@Wq+bq, bkf = bv@Wk+bk, zero WT rows 264..271
// blocks 257+   : CSR offsets via binary search (dst_idx sorted)
__global__ __launch_bounds__(256) void k_prep(
    const float* __restrict__ Wv, const float* __restrict__ bv,
    const float* __restrict__ Wq, const float* __restrict__ bq,
    const float* __restrict__ Wk, const float* __restrict__ bk,
    const int* __restrict__ dst_idx,
    unsigned short* __restrict__ WTbuf, float* __restrict__ Wvq,
    float* __restrict__ bvq, float* __restrict__ bkf, int* __restrict__ off) {
    const int b = blockIdx.x;
    const int tid = threadIdx.x;
    __shared__ float sq[4][8], sk[4][8];
    if (b < 257) {
        const int i = b;
        float vv = (i < 256) ? Wv[(size_t)i * HF_C + tid] : bv[tid];
        f32x4_t q0 = *(const f32x4_t*)(Wq + tid * 8);
        f32x4_t q1 = *(const f32x4_t*)(Wq + tid * 8 + 4);
        f32x4_t k0 = *(const f32x4_t*)(Wk + tid * 8);
        f32x4_t k1 = *(const f32x4_t*)(Wk + tid * 8 + 4);
        float pq[8], pk[8];
#pragma unroll
        for (int h = 0; h < 4; ++h) {
            pq[h] = vv * q0[h]; pq[4 + h] = vv * q1[h];
            pk[h] = vv * k0[h]; pk[4 + h] = vv * k1[h];
        }
#pragma unroll
        for (int m = 1; m < 64; m <<= 1) {
#pragma unroll
            for (int h = 0; h < 8; ++h) {
                pq[h] += __shfl_xor(pq[h], m);
                pk[h] += __shfl_xor(pk[h], m);
            }
        }
        const int w = tid >> 6, ln = tid & 63;
        if (ln == 0) {
#pragma unroll
            for (int h = 0; h < 8; ++h) { sq[w][h] = pq[h]; sk[w][h] = pk[h]; }
        }
        __syncthreads();
        if (tid < 8) {
            float fq = sq[0][tid] + sq[1][tid] + sq[2][tid] + sq[3][tid];
            float fk = sk[0][tid] + sk[1][tid] + sk[2][tid] + sk[3][tid];
            if (i < 256) {
                Wvq[i * 8 + tid] = fq;
                WTbuf[(256 + tid) * IN_FC + i] = f2bf(fk);
            } else {
                bvq[tid] = fq + bq[tid];
                bkf[tid] = fk + bk[tid];
            }
        }
        if (i < 256) {
            WTbuf[i * IN_FC + tid] = f2bf(Wv[(size_t)tid * HF_C + i]);
        } else {
#pragma unroll
            for (int j = 0; j < 8; ++j) WTbuf[264 * IN_FC + tid * 8 + j] = 0;
        }
    } else {
        int n = (b - 257) * 256 + tid;
        if (n > N_DST_C) return;
        if (n == N_DST_C) { off[n] = E_C; return; }
        int lo = 0, hi = E_C;
        while (lo < hi) {
            int mid = (lo + hi) >> 1;
            if (dst_idx[mid] < n) lo = mid + 1; else hi = mid;
        }
        off[n] = lo;
    }
}

// ---------------- K1: H = bf16(x_src @ Wv + bv), kk = x_src @ Wvk + bkf ----------------
// BM=128, BK=64, 512 threads = 8 waves (2 M x 4 N), wave tile 64x64 + 16-row aux quarter.
#define GPITCH 72   // 64 + 8 pad (16B) per LDS row

__global__ __launch_bounds__(512) void k_gemm(
    const float* __restrict__ X, const unsigned short* __restrict__ WTbuf,
    const float* __restrict__ bmain, const float* __restrict__ baux,
    unsigned short* __restrict__ H, float* __restrict__ auxo, int M) {
    __shared__ __align__(16) unsigned short As[128 * GPITCH];   // 18.4 KB
    __shared__ __align__(16) unsigned short Bs[272 * GPITCH];   // 39.2 KB
    const int tid = threadIdx.x;
    const int lane = tid & 63;
    const int wave = tid >> 6;
    const int wr = wave >> 2, wc = wave & 3;
    const int row0 = blockIdx.x * 128;

    f32x4_t acc[4][4];
    f32x4_t accA = {0.f, 0.f, 0.f, 0.f};
    const f32x4_t z = {0.f, 0.f, 0.f, 0.f};
#pragma unroll
    for (int m = 0; m < 4; ++m)
#pragma unroll
        for (int n = 0; n < 4; ++n) acc[m][n] = z;

    for (int k0 = 0; k0 < IN_FC; k0 += 64) {
        // A stage: 128 rows x 64 f32 -> bf16. thread: row=tid>>2, colgroup=tid&3 (16 cols)
        {
            const int row = tid >> 2, cg = tid & 3;
            int gr = row0 + row; if (gr >= M) gr = M - 1;
            const float* src = X + (size_t)gr * IN_FC + k0 + cg * 16;
            unsigned short* dst = As + row * GPITCH + cg * 16;
#pragma unroll
            for (int j = 0; j < 4; ++j) {
                f32x4_t xv = *(const f32x4_t*)(src + j * 4);
                unsigned int u0 = (unsigned int)f2bf(xv[0]) | ((unsigned int)f2bf(xv[1]) << 16);
                unsigned int u1 = (unsigned int)f2bf(xv[2]) | ((unsigned int)f2bf(xv[3]) << 16);
                uint2 uu; uu.x = u0; uu.y = u1;
                *(uint2*)(dst + j * 4) = uu;
            }
        }
        // B stage: rows 0..255 main + 256..271 aux, 64 bf16 cols each
#pragma unroll
        for (int i2 = 0; i2 < 4; ++i2) {
            int c = tid + i2 * 512;
            int rrow = c >> 3, cc = c & 7;
            uint4 v = *(const uint4*)(WTbuf + (size_t)rrow * IN_FC + k0 + cc * 8);
            *(uint4*)(Bs + rrow * GPITCH + cc * 8) = v;
        }
        if (tid < 128) {
            int rrow = 256 + (tid >> 3), cc = tid & 7;
            uint4 v = *(const uint4*)(WTbuf + (size_t)rrow * IN_FC + k0 + cc * 8);
            *(uint4*)(Bs + rrow * GPITCH + cc * 8) = v;
        }
        __syncthreads();
#pragma unroll
        for (int ks = 0; ks < 2; ++ks) {
            const int koff = ks * 32 + (lane >> 4) * 8;
            s16x8_t a[4];
#pragma unroll
            for (int m = 0; m < 4; ++m)
                a[m] = *(const s16x8_t*)(As + (wr * 64 + m * 16 + (lane & 15)) * GPITCH + koff);
            s16x8_t bf[4];
#pragma unroll
            for (int n = 0; n < 4; ++n)
                bf[n] = *(const s16x8_t*)(Bs + (wc * 64 + n * 16 + (lane & 15)) * GPITCH + koff);
#pragma unroll
            for (int m = 0; m < 4; ++m)
#pragma unroll
                for (int n = 0; n < 4; ++n)
                    acc[m][n] = __builtin_amdgcn_mfma_f32_16x16x32_bf16(a[m], bf[n], acc[m][n], 0, 0, 0);
            // aux: wave (wr,wc) covers rows wr*64 + wc*16 .. +15 (avoid dynamic a[wc] reg index)
            s16x8_t aa = *(const s16x8_t*)(As + (wr * 64 + wc * 16 + (lane & 15)) * GPITCH + koff);
            s16x8_t ba = *(const s16x8_t*)(Bs + (256 + (lane & 15)) * GPITCH + koff);
            accA = __builtin_amdgcn_mfma_f32_16x16x32_bf16(aa, ba, accA, 0, 0, 0);
        }
        __syncthreads();
    }
    // epilogue: H = bf16(acc + bv)
#pragma unroll
    for (int n = 0; n < 4; ++n) {
        int col = wc * 64 + n * 16 + (lane & 15);
        float bb = bmain[col];
#pragma unroll
        for (int m = 0; m < 4; ++m) {
            int rb = row0 + wr * 64 + m * 16 + (lane >> 4) * 4;
#pragma unroll
            for (int j = 0; j < 4; ++j) {
                int r = rb + j;
                if (r < M) H[(size_t)r * HF_C + col] = f2bf(acc[m][n][j] + bb);
            }
        }
    }
    // aux epilogue: kk
    {
        int col0 = lane & 15;
        if (col0 < 8) {
            float bb = baux[col0];
            int rb = row0 + wr * 64 + wc * 16 + (lane >> 4) * 4;
#pragma unroll
            for (int j = 0; j < 4; ++j) {
                int r = rb + j;
                if (r < M) auxo[(size_t)r * 8 + col0] = accA[j] + bb;
            }
        }
    }
}

// ---------------- K2: q = x_dst @ Wvq + bvq (f32, wave per row) ----------------
__global__ __launch_bounds__(256) void k_proj_f32(
    const float* __restrict__ X, const float* __restrict__ W8,
    const float* __restrict__ b8, float* __restrict__ outp, int M) {
    __shared__ float Ws[HEADS_C * HF_C];  // transposed: Ws[h][i]
    const int tid = threadIdx.x;
    for (int i = tid; i < HEADS_C * HF_C; i += 256) {
        int h = i >> 8, idx = i & 255;
        Ws[i] = W8[idx * HEADS_C + h];
    }
    __syncthreads();
    const int lane = tid & 63;
    const int row = blockIdx.x * 4 + (tid >> 6);
    if (row >= M) return;
    float x[4];
#pragma unroll
    for (int t = 0; t < 4; ++t) x[t] = X[(size_t)row * HF_C + lane + 64 * t];
    float p[8];
#pragma unroll
    for (int h = 0; h < 8; ++h) p[h] = 0.f;
#pragma unroll
    for (int t = 0; t < 4; ++t) {
        float xv = x[t];
#pragma unroll
        for (int h = 0; h < 8; ++h) p[h] += xv * Ws[h * 256 + lane + 64 * t];
    }
#pragma unroll
    for (int m = 1; m < 64; m <<= 1) {
#pragma unroll
        for (int h = 0; h < 8; ++h) p[h] += __shfl_xor(p[h], m);
    }
    if (lane < 8) outp[(size_t)row * 8 + lane] = p[lane] + b8[lane];
}

// ---------------- K3: single-pass online-softmax + aggregation, 16-edge tiles ----------------
// weight layout: lane = 8*e_sub + h_w  (8 edge-slots x 8 heads), two slots -> 16 edges/iter
// agg layout:    lane = 8*h_a + fc     (8 heads x 8 feature-chunks of 4)
__global__ __launch_bounds__(256) void k_gat_agg(
    const int* __restrict__ src_idx, const int* __restrict__ off,
    const float* __restrict__ q, const float* __restrict__ kk,
    const unsigned short* __restrict__ H, float* __restrict__ outp) {
    const int wv = (blockIdx.x * 256 + threadIdx.x) >> 6;
    const int lane = threadIdx.x & 63;
    if (wv >= N_DST_C) return;
    const int o0 = off[wv], o1 = off[wv + 1];
    const int e_sub = lane >> 3;
    const int h_w   = lane & 7;
    const int h_a   = lane >> 3;
    const float q_w = q[(size_t)wv * 8 + h_w];

    float m_w = -1e30f;
    float den_w = 0.f;
    float a0 = 0.f, a1 = 0.f, a2 = 0.f, a3 = 0.f;
    const unsigned short* Hb = H + (size_t)h_a * 32 + (lane & 7) * 4;

    for (int base = o0; base < o1; base += 16) {
        const int rem = o1 - base;            // wave-uniform
        const bool act0 = e_sub < rem;
        const bool act1 = e_sub + 8 < rem;
        const int s0 = act0 ? src_idx[base + e_sub] : 0;
        const int s1 = act1 ? src_idx[base + 8 + e_sub] : 0;
        const float kv0 = kk[(size_t)s0 * 8 + h_w];
        const float kv1 = kk[(size_t)s1 * 8 + h_w];
        float ev0 = q_w + kv0; ev0 = (ev0 >= 0.f) ? ev0 : 0.2f * ev0;
        float ev1 = q_w + kv1; ev1 = (ev1 >= 0.f) ? ev1 : 0.2f * ev1;
        if (!act0) ev0 = -1e30f;
        if (!act1) ev1 = -1e30f;
        float cm = fmaxf(ev0, ev1);
        cm = fmaxf(cm, __shfl_xor(cm, 8));
        cm = fmaxf(cm, __shfl_xor(cm, 16));
        cm = fmaxf(cm, __shfl_xor(cm, 32));
        if (!__all(cm <= m_w)) {
            float m_new = fmaxf(m_w, cm);
            float sc_w = __expf(m_w - m_new);
            den_w *= sc_w;
            float sc_a = __shfl(sc_w, h_a);
            a0 *= sc_a; a1 *= sc_a; a2 *= sc_a; a3 *= sc_a;
            m_w = m_new;
        }
        const float p0 = act0 ? __expf(ev0 - m_w) : 0.f;
        const float p1 = act1 ? __expf(ev1 - m_w) : 0.f;
        den_w += p0 + p1;
        const int ubase = __builtin_amdgcn_readfirstlane(base);
        if (rem >= 16) {
#pragma unroll
            for (int j = 0; j < 8; ++j) {
                float wgt = __shfl(p0, j * 8 + h_a);
                int se = src_idx[ubase + j];
                ushort4 xv = *(const ushort4*)(Hb + (size_t)se * 256);
                a0 += wgt * bf2f(xv.x); a1 += wgt * bf2f(xv.y);
                a2 += wgt * bf2f(xv.z); a3 += wgt * bf2f(xv.w);
            }
#pragma unroll
            for (int j = 0; j < 8; ++j) {
                float wgt = __shfl(p1, j * 8 + h_a);
                int se = src_idx[ubase + 8 + j];
                ushort4 xv = *(const ushort4*)(Hb + (size_t)se * 256);
                a0 += wgt * bf2f(xv.x); a1 += wgt * bf2f(xv.y);
                a2 += wgt * bf2f(xv.z); a3 += wgt * bf2f(xv.w);
            }
        } else {
            const int n0 = rem < 8 ? rem : 8;
            for (int j = 0; j < n0; ++j) {
                float wgt = __shfl(p0, j * 8 + h_a);
                int se = src_idx[ubase + j];
                ushort4 xv = *(const ushort4*)(Hb + (size_t)se * 256);
                a0 += wgt * bf2f(xv.x); a1 += wgt * bf2f(xv.y);
                a2 += wgt * bf2f(xv.z); a3 += wgt * bf2f(xv.w);
            }
            for (int j = 0; j < rem - 8; ++j) {
                float wgt = __shfl(p1, j * 8 + h_a);
                int se = src_idx[ubase + 8 + j];
                ushort4 xv = *(const ushort4*)(Hb + (size_t)se * 256);
                a0 += wgt * bf2f(xv.x); a1 += wgt * bf2f(xv.y);
                a2 += wgt * bf2f(xv.z); a3 += wgt * bf2f(xv.w);
            }
        }
    }
    den_w += __shfl_xor(den_w, 8);
    den_w += __shfl_xor(den_w, 16);
    den_w += __shfl_xor(den_w, 32);
    const float rs_w = 1.f / (den_w + 1e-9f);
    const float rs_a = __shfl(rs_w, h_a);
    a0 *= rs_a; a1 *= rs_a; a2 *= rs_a; a3 *= rs_a;
    a0 += __shfl_xor(a0, 8); a0 += __shfl_xor(a0, 16); a0 += __shfl_xor(a0, 32);
    a1 += __shfl_xor(a1, 8); a1 += __shfl_xor(a1, 16); a1 += __shfl_xor(a1, 32);
    a2 += __shfl_xor(a2, 8); a2 += __shfl_xor(a2, 16); a2 += __shfl_xor(a2, 32);
    a3 += __shfl_xor(a3, 8); a3 += __shfl_xor(a3, 16); a3 += __shfl_xor(a3, 32);
    if (lane < 8) {
        f32x4_t v = {a0 * 0.125f, a1 * 0.125f, a2 * 0.125f, a3 * 0.125f};
        *(f32x4_t*)(outp + (size_t)wv * 32 + lane * 4) = v;
    }
}

extern "C" void kernel_launch(void* const* d_in, const int* in_sizes, int n_in,
                              void* d_out, int out_size, void* d_ws, size_t ws_size,
                              hipStream_t stream) {
    const float* x_src = (const float*)d_in[0];
    const float* x_dst = (const float*)d_in[1];
    const float* Wv    = (const float*)d_in[2];
    const float* bv    = (const float*)d_in[3];
    const float* Wq    = (const float*)d_in[4];
    const float* bq    = (const float*)d_in[5];
    const float* Wk    = (const float*)d_in[6];
    const float* bk    = (const float*)d_in[7];
    const int* src_idx = (const int*)d_in[8];
    const int* dst_idx = (const int*)d_in[9];
    float* out = (float*)d_out;

    char* w = (char*)d_ws;
    unsigned short* H = (unsigned short*)w; w += (size_t)N_SRC_C * HF_C * 2;   // 51.2 MB
    float* q  = (float*)w; w += (size_t)N_DST_C * HEADS_C * 4;                 // 3.2 MB
    float* kk = (float*)w; w += (size_t)N_SRC_C * HEADS_C * 4;                 // 3.2 MB
    int* off  = (int*)w;   w += 400128;                                        // (N+1)*4 rounded
    unsigned short* WTbuf = (unsigned short*)w; w += (size_t)272 * IN_FC * 2;  // 139 KB
    float* Wvq = (float*)w; w += (size_t)IN_FC * HEADS_C * 4;                  // 8 KB
    float* bvq = (float*)w; w += 256;
    float* bkf = (float*)w; w += 256;

    k_prep<<<dim3(648), dim3(256), 0, stream>>>(Wv, bv, Wq, bq, Wk, bk, dst_idx,
                                                WTbuf, Wvq, bvq, bkf, off);
    k_gemm<<<dim3((N_SRC_C + 127) / 128), dim3(512), 0, stream>>>(
        x_src, WTbuf, bv, bkf, H, kk, N_SRC_C);
    k_proj_f32<<<dim3((N_DST_C + 3) / 4), dim3(256), 0, stream>>>(x_dst, Wvq, bvq, q, N_DST_C);
    k_gat_agg<<<dim3((N_DST_C + 3) / 4), dim3(256), 0, stream>>>(src_idx, off, q, kk, H, out);
}

// Round 4
// 315.987 us; speedup vs baseline: 1.5748x; 1.0866x over previous
//
#include <hip/hip_runtime.h>
#include <hip/hip_bf16.h>
#include <stdint.h>

#define N_SRC_C 100000
#define N_DST_C 100000
#define E_C     1600000
#define IN_FC   256
#define HEADS_C 8
#define OUT_FC  32
#define HF_C    256

typedef float f32x4_t __attribute__((ext_vector_type(4)));
typedef short s16x8_t __attribute__((ext_vector_type(8)));

static __device__ __forceinline__ unsigned short f2bf(float f) {
    union { __hip_bfloat16 h; unsigned short u; } cv;
    cv.h = __float2bfloat16(f);
    return cv.u;
}
static __device__ __forceinline__ float bf2f(unsigned short u) {
    return __uint_as_float(((unsigned int)u) << 16);
}

// ---------------- K0: fused prep ----------------
// blocks 0..255 : WT main row i (bf16 Wv^T) + Wvq row i (f32) + Wvk^T row (bf16, rows 256..263)
// block 256     : bvq = bv@Wq+bq, bkf = bv@Wk+bk, zero WT rows 264..271
// blocks 257+   : CSR offsets via binary search (dst_idx sorted)
__global__ __launch_bounds__(256) void k_prep(
    const float* __restrict__ Wv, const float* __restrict__ bv,
    const float* __restrict__ Wq, const float* __restrict__ bq,
    const float* __restrict__ Wk, const float* __restrict__ bk,
    const int* __restrict__ dst_idx,
    unsigned short* __restrict__ WTbuf, float* __restrict__ Wvq,
    float* __restrict__ bvq, float* __restrict__ bkf, int* __restrict__ off) {
    const int b = blockIdx.x;
    const int tid = threadIdx.x;
    __shared__ float sq[4][8], sk[4][8];
    if (b < 257) {
        const int i = b;
        float vv = (i < 256) ? Wv[(size_t)i * HF_C + tid] : bv[tid];
        f32x4_t q0 = *(const f32x4_t*)(Wq + tid * 8);
        f32x4_t q1 = *(const f32x4_t*)(Wq + tid * 8 + 4);
        f32x4_t k0 = *(const f32x4_t*)(Wk + tid * 8);
        f32x4_t k1 = *(const f32x4_t*)(Wk + tid * 8 + 4);
        float pq[8], pk[8];
#pragma unroll
        for (int h = 0; h < 4; ++h) {
            pq[h] = vv * q0[h]; pq[4 + h] = vv * q1[h];
            pk[h] = vv * k0[h]; pk[4 + h] = vv * k1[h];
        }
#pragma unroll
        for (int m = 1; m < 64; m <<= 1) {
#pragma unroll
            for (int h = 0; h < 8; ++h) {
                pq[h] += __shfl_xor(pq[h], m);
                pk[h] += __shfl_xor(pk[h], m);
            }
        }
        const int w = tid >> 6, ln = tid & 63;
        if (ln == 0) {
#pragma unroll
            for (int h = 0; h < 8; ++h) { sq[w][h] = pq[h]; sk[w][h] = pk[h]; }
        }
        __syncthreads();
        if (tid < 8) {
            float fq = sq[0][tid] + sq[1][tid] + sq[2][tid] + sq[3][tid];
            float fk = sk[0][tid] + sk[1][tid] + sk[2][tid] + sk[3][tid];
            if (i < 256) {
                Wvq[i * 8 + tid] = fq;
                WTbuf[(256 + tid) * IN_FC + i] = f2bf(fk);
            } else {
                bvq[tid] = fq + bq[tid];
                bkf[tid] = fk + bk[tid];
            }
        }
        if (i < 256) {
            WTbuf[i * IN_FC + tid] = f2bf(Wv[(size_t)tid * HF_C + i]);
        } else {
#pragma unroll
            for (int j = 0; j < 8; ++j) WTbuf[264 * IN_FC + tid * 8 + j] = 0;
        }
    } else {
        int n = (b - 257) * 256 + tid;
        if (n > N_DST_C) return;
        if (n == N_DST_C) { off[n] = E_C; return; }
        int lo = 0, hi = E_C;
        while (lo < hi) {
            int mid = (lo + hi) >> 1;
            if (dst_idx[mid] < n) lo = mid + 1; else hi = mid;
        }
        off[n] = lo;
    }
}

// ---------------- K1: H = bf16(x_src @ Wv + bv), kk = x_src @ Wvk + bkf ----------------
// BM=128, BK=64, 512 threads = 8 waves (2 M x 4 N), wave tile 64x64 + 16-row aux quarter.
#define GPITCH 72   // 64 + 8 pad (16B) per LDS row

__global__ __launch_bounds__(512) void k_gemm(
    const float* __restrict__ X, const unsigned short* __restrict__ WTbuf,
    const float* __restrict__ bmain, const float* __restrict__ baux,
    unsigned short* __restrict__ H, float* __restrict__ auxo, int M) {
    __shared__ __align__(16) unsigned short As[128 * GPITCH];   // 18.4 KB
    __shared__ __align__(16) unsigned short Bs[272 * GPITCH];   // 39.2 KB
    const int tid = threadIdx.x;
    const int lane = tid & 63;
    const int wave = tid >> 6;
    const int wr = wave >> 2, wc = wave & 3;
    const int row0 = blockIdx.x * 128;

    f32x4_t acc[4][4];
    f32x4_t accA = {0.f, 0.f, 0.f, 0.f};
    const f32x4_t z = {0.f, 0.f, 0.f, 0.f};
#pragma unroll
    for (int m = 0; m < 4; ++m)
#pragma unroll
        for (int n = 0; n < 4; ++n) acc[m][n] = z;

    for (int k0 = 0; k0 < IN_FC; k0 += 64) {
        {
            const int row = tid >> 2, cg = tid & 3;
            int gr = row0 + row; if (gr >= M) gr = M - 1;
            const float* src = X + (size_t)gr * IN_FC + k0 + cg * 16;
            unsigned short* dst = As + row * GPITCH + cg * 16;
#pragma unroll
            for (int j = 0; j < 4; ++j) {
                f32x4_t xv = *(const f32x4_t*)(src + j * 4);
                unsigned int u0 = (unsigned int)f2bf(xv[0]) | ((unsigned int)f2bf(xv[1]) << 16);
                unsigned int u1 = (unsigned int)f2bf(xv[2]) | ((unsigned int)f2bf(xv[3]) << 16);
                uint2 uu; uu.x = u0; uu.y = u1;
                *(uint2*)(dst + j * 4) = uu;
            }
        }
#pragma unroll
        for (int i2 = 0; i2 < 4; ++i2) {
            int c = tid + i2 * 512;
            int rrow = c >> 3, cc = c & 7;
            uint4 v = *(const uint4*)(WTbuf + (size_t)rrow * IN_FC + k0 + cc * 8);
            *(uint4*)(Bs + rrow * GPITCH + cc * 8) = v;
        }
        if (tid < 128) {
            int rrow = 256 + (tid >> 3), cc = tid & 7;
            uint4 v = *(const uint4*)(WTbuf + (size_t)rrow * IN_FC + k0 + cc * 8);
            *(uint4*)(Bs + rrow * GPITCH + cc * 8) = v;
        }
        __syncthreads();
#pragma unroll
        for (int ks = 0; ks < 2; ++ks) {
            const int koff = ks * 32 + (lane >> 4) * 8;
            s16x8_t a[4];
#pragma unroll
            for (int m = 0; m < 4; ++m)
                a[m] = *(const s16x8_t*)(As + (wr * 64 + m * 16 + (lane & 15)) * GPITCH + koff);
            s16x8_t bf[4];
#pragma unroll
            for (int n = 0; n < 4; ++n)
                bf[n] = *(const s16x8_t*)(Bs + (wc * 64 + n * 16 + (lane & 15)) * GPITCH + koff);
#pragma unroll
            for (int m = 0; m < 4; ++m)
#pragma unroll
                for (int n = 0; n < 4; ++n)
                    acc[m][n] = __builtin_amdgcn_mfma_f32_16x16x32_bf16(a[m], bf[n], acc[m][n], 0, 0, 0);
            s16x8_t aa = *(const s16x8_t*)(As + (wr * 64 + wc * 16 + (lane & 15)) * GPITCH + koff);
            s16x8_t ba = *(const s16x8_t*)(Bs + (256 + (lane & 15)) * GPITCH + koff);
            accA = __builtin_amdgcn_mfma_f32_16x16x32_bf16(aa, ba, accA, 0, 0, 0);
        }
        __syncthreads();
    }
#pragma unroll
    for (int n = 0; n < 4; ++n) {
        int col = wc * 64 + n * 16 + (lane & 15);
        float bb = bmain[col];
#pragma unroll
        for (int m = 0; m < 4; ++m) {
            int rb = row0 + wr * 64 + m * 16 + (lane >> 4) * 4;
#pragma unroll
            for (int j = 0; j < 4; ++j) {
                int r = rb + j;
                if (r < M) H[(size_t)r * HF_C + col] = f2bf(acc[m][n][j] + bb);
            }
        }
    }
    {
        int col0 = lane & 15;
        if (col0 < 8) {
            float bb = baux[col0];
            int rb = row0 + wr * 64 + wc * 16 + (lane >> 4) * 4;
#pragma unroll
            for (int j = 0; j < 4; ++j) {
                int r = rb + j;
                if (r < M) auxo[(size_t)r * 8 + col0] = accA[j] + bb;
            }
        }
    }
}

// ---------------- K2: q = x_dst @ Wvq + bvq (f32, wave per row) ----------------
__global__ __launch_bounds__(256) void k_proj_f32(
    const float* __restrict__ X, const float* __restrict__ W8,
    const float* __restrict__ b8, float* __restrict__ outp, int M) {
    __shared__ float Ws[HEADS_C * HF_C];  // transposed: Ws[h][i]
    const int tid = threadIdx.x;
    for (int i = tid; i < HEADS_C * HF_C; i += 256) {
        int h = i >> 8, idx = i & 255;
        Ws[i] = W8[idx * HEADS_C + h];
    }
    __syncthreads();
    const int lane = tid & 63;
    const int row = blockIdx.x * 4 + (tid >> 6);
    if (row >= M) return;
    float x[4];
#pragma unroll
    for (int t = 0; t < 4; ++t) x[t] = X[(size_t)row * HF_C + lane + 64 * t];
    float p[8];
#pragma unroll
    for (int h = 0; h < 8; ++h) p[h] = 0.f;
#pragma unroll
    for (int t = 0; t < 4; ++t) {
        float xv = x[t];
#pragma unroll
        for (int h = 0; h < 8; ++h) p[h] += xv * Ws[h * 256 + lane + 64 * t];
    }
#pragma unroll
    for (int m = 1; m < 64; m <<= 1) {
#pragma unroll
        for (int h = 0; h < 8; ++h) p[h] += __shfl_xor(p[h], m);
    }
    if (lane < 8) outp[(size_t)row * 8 + lane] = p[lane] + b8[lane];
}

// ---------------- K3: no-max softmax + aggregation, clamped 16-edge tiles, prefetch ----------------
// weight layout: lane = 8*e_sub + h_w  (8 edge-slots x 8 heads)
// agg layout:    lane = 8*h_a + fc     (8 heads x 8 feature-chunks of 4)
__global__ __launch_bounds__(256) void k_gat_agg(
    const int* __restrict__ src_idx, const int* __restrict__ off,
    const float* __restrict__ q, const float* __restrict__ kk,
    const unsigned short* __restrict__ H, float* __restrict__ outp) {
    const int wv = (blockIdx.x * 256 + threadIdx.x) >> 6;
    const int lane = threadIdx.x & 63;
    if (wv >= N_DST_C) return;
    const int o0 = off[wv], o1 = off[wv + 1];
    const int e_sub = lane >> 3;
    const int h_w   = lane & 7;
    const int h_a   = lane >> 3;
    if (o1 <= o0) {   // degree-0 node -> zeros
        if (lane < 8) {
            f32x4_t zv = {0.f, 0.f, 0.f, 0.f};
            *(f32x4_t*)(outp + (size_t)wv * 32 + lane * 4) = zv;
        }
        return;
    }
    const float q_w = q[(size_t)wv * 8 + h_w];
    const int last = o1 - 1;
    float den_w = 0.f;
    float a0 = 0.f, a1 = 0.f, a2 = 0.f, a3 = 0.f;
    const unsigned short* Hb = H + (size_t)h_a * 32 + (lane & 7) * 4;

    // prefetch tile 0 edge indices (clamped -> always valid, branchless)
    int s0 = src_idx[min(o0 + e_sub, last)];
    int s1 = src_idx[min(o0 + 8 + e_sub, last)];

    for (int base = o0; base < o1; base += 16) {
        const float kv0 = kk[(size_t)s0 * 8 + h_w];
        const float kv1 = kk[(size_t)s1 * 8 + h_w];
        // prefetch next tile (clamped; L1-hit if past end)
        const int sn0 = src_idx[min(base + 16 + e_sub, last)];
        const int sn1 = src_idx[min(base + 24 + e_sub, last)];
        float ev0 = q_w + kv0; ev0 = (ev0 >= 0.f) ? ev0 : 0.2f * ev0;
        float ev1 = q_w + kv1; ev1 = (ev1 >= 0.f) ? ev1 : 0.2f * ev1;
        // no max subtraction: |ev| <~ 6, exp safe in f32; matches ref to rounding
        const float p0 = (base + e_sub < o1) ? __expf(ev0) : 0.f;
        const float p1 = (base + 8 + e_sub < o1) ? __expf(ev1) : 0.f;
        den_w += p0 + p1;
#pragma unroll
        for (int j = 0; j < 8; ++j) {
            const float wgt = __shfl(p0, j * 8 + h_a);
            const int se = __shfl(s0, j * 8);
            const uint2 xv = *(const uint2*)(Hb + (size_t)se * 256);
            a0 += wgt * __uint_as_float(xv.x << 16);
            a1 += wgt * __uint_as_float(xv.x & 0xffff0000u);
            a2 += wgt * __uint_as_float(xv.y << 16);
            a3 += wgt * __uint_as_float(xv.y & 0xffff0000u);
        }
#pragma unroll
        for (int j = 0; j < 8; ++j) {
            const float wgt = __shfl(p1, j * 8 + h_a);
            const int se = __shfl(s1, j * 8);
            const uint2 xv = *(const uint2*)(Hb + (size_t)se * 256);
            a0 += wgt * __uint_as_float(xv.x << 16);
            a1 += wgt * __uint_as_float(xv.x & 0xffff0000u);
            a2 += wgt * __uint_as_float(xv.y << 16);
            a3 += wgt * __uint_as_float(xv.y & 0xffff0000u);
        }
        s0 = sn0; s1 = sn1;
    }
    den_w += __shfl_xor(den_w, 8);
    den_w += __shfl_xor(den_w, 16);
    den_w += __shfl_xor(den_w, 32);
    const float rs_w = 1.f / (den_w + 1e-9f);
    const float rs_a = __shfl(rs_w, h_a);
    a0 *= rs_a; a1 *= rs_a; a2 *= rs_a; a3 *= rs_a;
    a0 += __shfl_xor(a0, 8); a0 += __shfl_xor(a0, 16); a0 += __shfl_xor(a0, 32);
    a1 += __shfl_xor(a1, 8); a1 += __shfl_xor(a1, 16); a1 += __shfl_xor(a1, 32);
    a2 += __shfl_xor(a2, 8); a2 += __shfl_xor(a2, 16); a2 += __shfl_xor(a2, 32);
    a3 += __shfl_xor(a3, 8); a3 += __shfl_xor(a3, 16); a3 += __shfl_xor(a3, 32);
    if (lane < 8) {
        f32x4_t v = {a0 * 0.125f, a1 * 0.125f, a2 * 0.125f, a3 * 0.125f};
        *(f32x4_t*)(outp + (size_t)wv * 32 + lane * 4) = v;
    }
}

extern "C" void kernel_launch(void* const* d_in, const int* in_sizes, int n_in,
                              void* d_out, int out_size, void* d_ws, size_t ws_size,
                              hipStream_t stream) {
    const float* x_src = (const float*)d_in[0];
    const float* x_dst = (const float*)d_in[1];
    const float* Wv    = (const float*)d_in[2];
    const float* bv    = (const float*)d_in[3];
    const float* Wq    = (const float*)d_in[4];
    const float* bq    = (const float*)d_in[5];
    const float* Wk    = (const float*)d_in[6];
    const float* bk    = (const float*)d_in[7];
    const int* src_idx = (const int*)d_in[8];
    const int* dst_idx = (const int*)d_in[9];
    float* out = (float*)d_out;

    char* w = (char*)d_ws;
    unsigned short* H = (unsigned short*)w; w += (size_t)N_SRC_C * HF_C * 2;   // 51.2 MB
    float* q  = (float*)w; w += (size_t)N_DST_C * HEADS_C * 4;                 // 3.2 MB
    float* kk = (float*)w; w += (size_t)N_SRC_C * HEADS_C * 4;                 // 3.2 MB
    int* off  = (int*)w;   w += 400128;                                        // (N+1)*4 rounded
    unsigned short* WTbuf = (unsigned short*)w; w += (size_t)272 * IN_FC * 2;  // 139 KB
    float* Wvq = (float*)w; w += (size_t)IN_FC * HEADS_C * 4;                  // 8 KB
    float* bvq = (float*)w; w += 256;
    float* bkf = (float*)w; w += 256;

    k_prep<<<dim3(648), dim3(256), 0, stream>>>(Wv, bv, Wq, bq, Wk, bk, dst_idx,
                                                WTbuf, Wvq, bvq, bkf, off);
    k_gemm<<<dim3((N_SRC_C + 127) / 128), dim3(512), 0, stream>>>(
        x_src, WTbuf, bv, bkf, H, kk, N_SRC_C);
    k_proj_f32<<<dim3((N_DST_C + 3) / 4), dim3(256), 0, stream>>>(x_dst, Wvq, bvq, q, N_DST_C);
    k_gat_agg<<<dim3((N_DST_C + 3) / 4), dim3(256), 0, stream>>>(src_idx, off, q, kk, H, out);
}

// Round 5
// 261.019 us; speedup vs baseline: 1.9064x; 1.2106x over previous
//
#include <hip/hip_runtime.h>
#include <hip/hip_bf16.h>
#include <stdint.h>

#define N_SRC_C 100000
#define N_DST_C 100000
#define M_TOT   200000
#define E_C     1600000
#define IN_FC   256
#define HEADS_C 8
#define OUT_FC  32
#define HF_C    256

typedef float f32x4_t __attribute__((ext_vector_type(4)));
typedef short s16x8_t __attribute__((ext_vector_type(8)));

static __device__ __forceinline__ unsigned short f2bf(float f) {
    union { __hip_bfloat16 h; unsigned short u; } cv;
    cv.h = __float2bfloat16(f);
    return cv.u;
}

// ---------------- K0: fused prep ----------------
// blocks 0..255 : WTbuf row i = bf16(Wv^T) ; aux rows 256+h = Wvk^T, 264+h = Wvq^T
// block 256     : baux16[0..7]=bv@Wk+bk, [8..15]=bv@Wq+bq
// blocks 257+   : CSR offsets via binary search (dst_idx sorted)
__global__ __launch_bounds__(256) void k_prep(
    const float* __restrict__ Wv, const float* __restrict__ bv,
    const float* __restrict__ Wq, const float* __restrict__ bq,
    const float* __restrict__ Wk, const float* __restrict__ bk,
    const int* __restrict__ dst_idx,
    unsigned short* __restrict__ WTbuf, float* __restrict__ baux16,
    int* __restrict__ off) {
    const int b = blockIdx.x;
    const int tid = threadIdx.x;
    __shared__ float sq[4][8], sk[4][8];
    if (b < 257) {
        const int i = b;
        float vv = (i < 256) ? Wv[(size_t)i * HF_C + tid] : bv[tid];
        f32x4_t q0 = *(const f32x4_t*)(Wq + tid * 8);
        f32x4_t q1 = *(const f32x4_t*)(Wq + tid * 8 + 4);
        f32x4_t k0 = *(const f32x4_t*)(Wk + tid * 8);
        f32x4_t k1 = *(const f32x4_t*)(Wk + tid * 8 + 4);
        float pq[8], pk[8];
#pragma unroll
        for (int h = 0; h < 4; ++h) {
            pq[h] = vv * q0[h]; pq[4 + h] = vv * q1[h];
            pk[h] = vv * k0[h]; pk[4 + h] = vv * k1[h];
        }
#pragma unroll
        for (int m = 1; m < 64; m <<= 1) {
#pragma unroll
            for (int h = 0; h < 8; ++h) {
                pq[h] += __shfl_xor(pq[h], m);
                pk[h] += __shfl_xor(pk[h], m);
            }
        }
        const int w = tid >> 6, ln = tid & 63;
        if (ln == 0) {
#pragma unroll
            for (int h = 0; h < 8; ++h) { sq[w][h] = pq[h]; sk[w][h] = pk[h]; }
        }
        __syncthreads();
        if (tid < 8) {
            float fq = sq[0][tid] + sq[1][tid] + sq[2][tid] + sq[3][tid];
            float fk = sk[0][tid] + sk[1][tid] + sk[2][tid] + sk[3][tid];
            if (i < 256) {
                WTbuf[(256 + tid) * IN_FC + i] = f2bf(fk);   // Wvk^T
                WTbuf[(264 + tid) * IN_FC + i] = f2bf(fq);   // Wvq^T
            } else {
                baux16[tid]     = fk + bk[tid];
                baux16[8 + tid] = fq + bq[tid];
            }
        }
        if (i < 256) WTbuf[i * IN_FC + tid] = f2bf(Wv[(size_t)tid * HF_C + i]);
    } else {
        int n = (b - 257) * 256 + tid;
        if (n > N_DST_C) return;
        if (n == N_DST_C) { off[n] = E_C; return; }
        int lo = 0, hi = E_C;
        while (lo < hi) {
            int mid = (lo + hi) >> 1;
            if (dst_idx[mid] < n) lo = mid + 1; else hi = mid;
        }
        off[n] = lo;
    }
}

// ---------------- K1: merged GEMM over [x_src; x_dst] ----------------
// main 256 cols = Wv (H for src rows only); aux 16 cols = [Wvk | Wvq]
// src rows: H(bf16) + kk(f32, aux cols 0..7); dst rows: q(f32, aux cols 8..15)
#define GPITCH 72   // 64 + 8 pad per LDS row

__global__ __launch_bounds__(512) void k_gemm(
    const float* __restrict__ Xs, const float* __restrict__ Xd,
    const unsigned short* __restrict__ WTbuf,
    const float* __restrict__ bmain, const float* __restrict__ baux16,
    unsigned short* __restrict__ H, float* __restrict__ kko, float* __restrict__ qo) {
    __shared__ __align__(16) unsigned short As[128 * GPITCH];   // 18.4 KB
    __shared__ __align__(16) unsigned short Bs[272 * GPITCH];   // 39.2 KB
    const int tid = threadIdx.x;
    const int lane = tid & 63;
    const int wave = tid >> 6;
    const int wr = wave >> 2, wc = wave & 3;
    const int row0 = blockIdx.x * 128;

    f32x4_t acc[4][4];
    f32x4_t accA = {0.f, 0.f, 0.f, 0.f};
    const f32x4_t z = {0.f, 0.f, 0.f, 0.f};
#pragma unroll
    for (int m = 0; m < 4; ++m)
#pragma unroll
        for (int n = 0; n < 4; ++n) acc[m][n] = z;

    for (int k0 = 0; k0 < IN_FC; k0 += 64) {
        {
            const int row = tid >> 2, cg = tid & 3;
            int gr = row0 + row; if (gr >= M_TOT) gr = M_TOT - 1;
            const float* src = (gr < N_SRC_C)
                ? (Xs + (size_t)gr * IN_FC + k0 + cg * 16)
                : (Xd + (size_t)(gr - N_SRC_C) * IN_FC + k0 + cg * 16);
            unsigned short* dst = As + row * GPITCH + cg * 16;
#pragma unroll
            for (int j = 0; j < 4; ++j) {
                f32x4_t xv = *(const f32x4_t*)(src + j * 4);
                unsigned int u0 = (unsigned int)f2bf(xv[0]) | ((unsigned int)f2bf(xv[1]) << 16);
                unsigned int u1 = (unsigned int)f2bf(xv[2]) | ((unsigned int)f2bf(xv[3]) << 16);
                uint2 uu; uu.x = u0; uu.y = u1;
                *(uint2*)(dst + j * 4) = uu;
            }
        }
#pragma unroll
        for (int i2 = 0; i2 < 4; ++i2) {
            int c = tid + i2 * 512;
            int rrow = c >> 3, cc = c & 7;
            uint4 v = *(const uint4*)(WTbuf + (size_t)rrow * IN_FC + k0 + cc * 8);
            *(uint4*)(Bs + rrow * GPITCH + cc * 8) = v;
        }
        if (tid < 128) {
            int rrow = 256 + (tid >> 3), cc = tid & 7;
            uint4 v = *(const uint4*)(WTbuf + (size_t)rrow * IN_FC + k0 + cc * 8);
            *(uint4*)(Bs + rrow * GPITCH + cc * 8) = v;
        }
        __syncthreads();
#pragma unroll
        for (int ks = 0; ks < 2; ++ks) {
            const int koff = ks * 32 + (lane >> 4) * 8;
            s16x8_t a[4];
#pragma unroll
            for (int m = 0; m < 4; ++m)
                a[m] = *(const s16x8_t*)(As + (wr * 64 + m * 16 + (lane & 15)) * GPITCH + koff);
            s16x8_t bf[4];
#pragma unroll
            for (int n = 0; n < 4; ++n)
                bf[n] = *(const s16x8_t*)(Bs + (wc * 64 + n * 16 + (lane & 15)) * GPITCH + koff);
#pragma unroll
            for (int m = 0; m < 4; ++m)
#pragma unroll
                for (int n = 0; n < 4; ++n)
                    acc[m][n] = __builtin_amdgcn_mfma_f32_16x16x32_bf16(a[m], bf[n], acc[m][n], 0, 0, 0);
            // aux: wave (wr,wc) covers rows wr*64 + wc*16 .. +15
            s16x8_t aa = *(const s16x8_t*)(As + (wr * 64 + wc * 16 + (lane & 15)) * GPITCH + koff);
            s16x8_t ba = *(const s16x8_t*)(Bs + (256 + (lane & 15)) * GPITCH + koff);
            accA = __builtin_amdgcn_mfma_f32_16x16x32_bf16(aa, ba, accA, 0, 0, 0);
        }
        __syncthreads();
    }
    // main epilogue: H = bf16(acc + bv) for src rows only
    if (row0 < N_SRC_C) {
#pragma unroll
        for (int n = 0; n < 4; ++n) {
            int col = wc * 64 + n * 16 + (lane & 15);
            float bb = bmain[col];
#pragma unroll
            for (int m = 0; m < 4; ++m) {
                int rb = row0 + wr * 64 + m * 16 + (lane >> 4) * 4;
#pragma unroll
                for (int j = 0; j < 4; ++j) {
                    int r = rb + j;
                    if (r < N_SRC_C) H[(size_t)r * HF_C + col] = f2bf(acc[m][n][j] + bb);
                }
            }
        }
    }
    // aux epilogue: kk (src rows, cols 0..7) / q (dst rows, cols 8..15)
    {
        int col0 = lane & 15;
        float bb = baux16[col0];
        int rb = row0 + wr * 64 + wc * 16 + (lane >> 4) * 4;
#pragma unroll
        for (int j = 0; j < 4; ++j) {
            int r = rb + j;
            if (r < M_TOT) {
                float v = accA[j] + bb;
                if (r < N_SRC_C) {
                    if (col0 < 8) kko[(size_t)r * 8 + col0] = v;
                } else {
                    if (col0 >= 8) qo[(size_t)(r - N_SRC_C) * 8 + (col0 - 8)] = v;
                }
            }
        }
    }
}

// ---------------- K2: edge weights w[e][h] = exp(leakyrelu(q[dst]+k[src])) ----------------
__global__ __launch_bounds__(256) void k_edgew(
    const int* __restrict__ src_idx, const int* __restrict__ dst_idx,
    const float* __restrict__ q, const float* __restrict__ kk,
    float* __restrict__ w) {
    const int e = blockIdx.x * 256 + threadIdx.x;
    const int s = src_idx[e];
    const int d = dst_idx[e];
    f32x4_t q0 = *(const f32x4_t*)(q + (size_t)d * 8);
    f32x4_t q1 = *(const f32x4_t*)(q + (size_t)d * 8 + 4);
    f32x4_t k0 = *(const f32x4_t*)(kk + (size_t)s * 8);
    f32x4_t k1 = *(const f32x4_t*)(kk + (size_t)s * 8 + 4);
    f32x4_t w0, w1;
#pragma unroll
    for (int h = 0; h < 4; ++h) {
        float e0 = q0[h] + k0[h]; e0 = (e0 >= 0.f) ? e0 : 0.2f * e0;
        float e1 = q1[h] + k1[h]; e1 = (e1 >= 0.f) ? e1 : 0.2f * e1;
        w0[h] = __expf(e0);
        w1[h] = __expf(e1);
    }
    *(f32x4_t*)(w + (size_t)e * 8) = w0;
    *(f32x4_t*)(w + (size_t)e * 8 + 4) = w1;
}

// ---------------- K3: aggregation with precomputed weights (wave per dst) ----------------
// den layout:  lane = 8*e_sub + h_w  (8 edge-slots x 8 heads)
// agg layout:  lane = 8*h_a + fc     (8 heads x 8 feature-chunks of 4)
__global__ __launch_bounds__(256) void k_gat_agg(
    const int* __restrict__ src_idx, const int* __restrict__ off,
    const float* __restrict__ w, const unsigned short* __restrict__ H,
    float* __restrict__ outp) {
    const int wv = (blockIdx.x * 256 + threadIdx.x) >> 6;
    const int lane = threadIdx.x & 63;
    if (wv >= N_DST_C) return;
    const int o0 = off[wv], o1 = off[wv + 1];
    const int e_sub = lane >> 3;
    const int h_w   = lane & 7;
    const int h_a   = lane >> 3;
    if (o1 <= o0) {
        if (lane < 8) {
            f32x4_t zv = {0.f, 0.f, 0.f, 0.f};
            *(f32x4_t*)(outp + (size_t)wv * 32 + lane * 4) = zv;
        }
        return;
    }
    const int last = o1 - 1;
    float den_w = 0.f;
    float a0 = 0.f, a1 = 0.f, a2 = 0.f, a3 = 0.f;
    const unsigned short* Hb = H + (size_t)h_a * 32 + (lane & 7) * 4;

    // prefetch tile 0 (clamped, branchless): indices + weights
    int s0 = src_idx[min(o0 + e_sub, last)];
    int s1 = src_idx[min(o0 + 8 + e_sub, last)];
    float w0 = w[(size_t)min(o0 + e_sub, last) * 8 + h_w];
    float w1 = w[(size_t)min(o0 + 8 + e_sub, last) * 8 + h_w];

    for (int base = o0; base < o1; base += 16) {
        const float p0 = (base + e_sub < o1) ? w0 : 0.f;
        const float p1 = (base + 8 + e_sub < o1) ? w1 : 0.f;
        den_w += p0 + p1;
        // batched gathers group A (all loads in flight before FMA)
        uint2 xa[8];
#pragma unroll
        for (int j = 0; j < 8; ++j) {
            const int se = __shfl(s0, j * 8);
            xa[j] = *(const uint2*)(Hb + (size_t)se * 256);
        }
        // prefetch next tile while gathers are in flight
        const int sn0 = src_idx[min(base + 16 + e_sub, last)];
        const int sn1 = src_idx[min(base + 24 + e_sub, last)];
        const float wn0 = w[(size_t)min(base + 16 + e_sub, last) * 8 + h_w];
        const float wn1 = w[(size_t)min(base + 24 + e_sub, last) * 8 + h_w];
#pragma unroll
        for (int j = 0; j < 8; ++j) {
            const float wgt = __shfl(p0, j * 8 + h_a);
            a0 += wgt * __uint_as_float(xa[j].x << 16);
            a1 += wgt * __uint_as_float(xa[j].x & 0xffff0000u);
            a2 += wgt * __uint_as_float(xa[j].y << 16);
            a3 += wgt * __uint_as_float(xa[j].y & 0xffff0000u);
        }
        // batched gathers group B
        uint2 xb[8];
#pragma unroll
        for (int j = 0; j < 8; ++j) {
            const int se = __shfl(s1, j * 8);
            xb[j] = *(const uint2*)(Hb + (size_t)se * 256);
        }
#pragma unroll
        for (int j = 0; j < 8; ++j) {
            const float wgt = __shfl(p1, j * 8 + h_a);
            a0 += wgt * __uint_as_float(xb[j].x << 16);
            a1 += wgt * __uint_as_float(xb[j].x & 0xffff0000u);
            a2 += wgt * __uint_as_float(xb[j].y << 16);
            a3 += wgt * __uint_as_float(xb[j].y & 0xffff0000u);
        }
        s0 = sn0; s1 = sn1; w0 = wn0; w1 = wn1;
    }
    den_w += __shfl_xor(den_w, 8);
    den_w += __shfl_xor(den_w, 16);
    den_w += __shfl_xor(den_w, 32);
    const float rs_w = 1.f / (den_w + 1e-9f);
    const float rs_a = __shfl(rs_w, h_a);
    a0 *= rs_a; a1 *= rs_a; a2 *= rs_a; a3 *= rs_a;
    a0 += __shfl_xor(a0, 8); a0 += __shfl_xor(a0, 16); a0 += __shfl_xor(a0, 32);
    a1 += __shfl_xor(a1, 8); a1 += __shfl_xor(a1, 16); a1 += __shfl_xor(a1, 32);
    a2 += __shfl_xor(a2, 8); a2 += __shfl_xor(a2, 16); a2 += __shfl_xor(a2, 32);
    a3 += __shfl_xor(a3, 8); a3 += __shfl_xor(a3, 16); a3 += __shfl_xor(a3, 32);
    if (lane < 8) {
        f32x4_t v = {a0 * 0.125f, a1 * 0.125f, a2 * 0.125f, a3 * 0.125f};
        *(f32x4_t*)(outp + (size_t)wv * 32 + lane * 4) = v;
    }
}

extern "C" void kernel_launch(void* const* d_in, const int* in_sizes, int n_in,
                              void* d_out, int out_size, void* d_ws, size_t ws_size,
                              hipStream_t stream) {
    const float* x_src = (const float*)d_in[0];
    const float* x_dst = (const float*)d_in[1];
    const float* Wv    = (const float*)d_in[2];
    const float* bv    = (const float*)d_in[3];
    const float* Wq    = (const float*)d_in[4];
    const float* bq    = (const float*)d_in[5];
    const float* Wk    = (const float*)d_in[6];
    const float* bk    = (const float*)d_in[7];
    const int* src_idx = (const int*)d_in[8];
    const int* dst_idx = (const int*)d_in[9];
    float* out = (float*)d_out;

    char* w = (char*)d_ws;
    unsigned short* H = (unsigned short*)w; w += (size_t)N_SRC_C * HF_C * 2;   // 51.2 MB
    float* q  = (float*)w; w += (size_t)N_DST_C * HEADS_C * 4;                 // 3.2 MB
    float* kk = (float*)w; w += (size_t)N_SRC_C * HEADS_C * 4;                 // 3.2 MB
    float* ew = (float*)w; w += (size_t)E_C * HEADS_C * 4;                     // 51.2 MB
    int* off  = (int*)w;   w += 400128;                                        // (N+1)*4 rounded
    unsigned short* WTbuf = (unsigned short*)w; w += (size_t)272 * IN_FC * 2;  // 139 KB
    float* baux16 = (float*)w; w += 256;

    k_prep<<<dim3(648), dim3(256), 0, stream>>>(Wv, bv, Wq, bq, Wk, bk, dst_idx,
                                                WTbuf, baux16, off);
    k_gemm<<<dim3((M_TOT + 127) / 128), dim3(512), 0, stream>>>(
        x_src, x_dst, WTbuf, bv, baux16, H, kk, q);
    k_edgew<<<dim3(E_C / 256), dim3(256), 0, stream>>>(src_idx, dst_idx, q, kk, ew);
    k_gat_agg<<<dim3((N_DST_C + 3) / 4), dim3(256), 0, stream>>>(src_idx, off, ew, H, out);
}